// Round 12
// baseline (63.610 us; speedup 1.0000x reference)
//
#include <hip/hip_runtime.h>

typedef float v2f __attribute__((ext_vector_type(2)));

#define D_DIM 512
#define C_CLS 100
#define SAMP 4     // samples per block; grid 1024
#define NT 256     // cq = t>>3 (0..31, active <25), dq = t&7

// ---- gsq[c] = sum_d grp[d][c]^2 -> ws[0..100)
__global__ __launch_bounds__(128) void gsq_kernel(const float* __restrict__ grp,
                                                  float* __restrict__ ws) {
    __shared__ float4 red[128];
    const int t = threadIdx.x;
    const int cb = blockIdx.x * 4;
    float4 acc = {0.f, 0.f, 0.f, 0.f};
    for (int d = t; d < D_DIM; d += 128) {
        float4 g = *(const float4*)&grp[d * C_CLS + cb];
        acc.x = fmaf(g.x, g.x, acc.x);
        acc.y = fmaf(g.y, g.y, acc.y);
        acc.z = fmaf(g.z, g.z, acc.z);
        acc.w = fmaf(g.w, g.w, acc.w);
    }
    red[t] = acc;
    __syncthreads();
    for (int off = 64; off > 0; off >>= 1) {
        if (t < off) {
            float4 a = red[t], b = red[t + off];
            a.x += b.x; a.y += b.y; a.z += b.z; a.w += b.w;
            red[t] = a;
        }
        __syncthreads();
    }
    if (t == 0) *(float4*)&ws[cb] = red[0];
}

// Main: thread (cq, dq) computes 4 classes x 4 samples over 64 interleaved d.
// dq partials reduced IN-WAVE via shfl_xor (no LDS partial arrays).
__global__ __launch_bounds__(NT, 5) void cls_kernel(const float* __restrict__ X,
                                                    const float* __restrict__ grp,
                                                    const float* __restrict__ gsq,
                                                    float* __restrict__ out) {
    __shared__ float4 pL1[SAMP][25];
    __shared__ float4 pDT[SAMP][25];
    __shared__ float redA[SAMP][25];
    __shared__ float redB[SAMP][25];
    __shared__ float xsqs[SAMP];

    const int t = threadIdx.x;
    const int n0 = blockIdx.x * SAMP;
    const float* xb = X + (size_t)n0 * D_DIM;
    const int cq = t >> 3;
    const int dq = t & 7;

    // xsq: cq==25 group (t 200..207), 2 lanes per sample row
    if (cq == 25) {
        const int l = t & 7, si = l >> 1, half = l & 1;
        const float* xr = xb + si * D_DIM + half * 256;
        v2f acc = {0.f, 0.f};
        for (int d4 = 0; d4 < 256; d4 += 4) {
            float4 a = *(const float4*)&xr[d4];
            v2f u = {a.x, a.y}, w = {a.z, a.w};
            acc += u * u;
            acc += w * w;
        }
        float v = acc.x + acc.y;
        v += __shfl_xor(v, 1);
        if (half == 0) xsqs[si] = v;
    }

    float l1[SAMP][4];
    v2f dtl[SAMP], dth[SAMP];
#pragma unroll
    for (int i = 0; i < SAMP; ++i) {
        dtl[i] = (v2f){0.f, 0.f};
        dth[i] = (v2f){0.f, 0.f};
#pragma unroll
        for (int j = 0; j < 4; ++j) l1[i][j] = 0.f;
    }

    if (cq < 25) {
        const float* gp = grp + cq * 4;
#pragma unroll 1
        for (int j = 0; j < 16; ++j) {
            const int d4 = j * 32 + dq * 4;   // block window: 32 rows = 12.8 KB
            float xr[SAMP][4];
#pragma unroll
            for (int si = 0; si < SAMP; ++si)
                *(float4*)&xr[si][0] = *(const float4*)&xb[si * D_DIM + d4];
#pragma unroll
            for (int k = 0; k < 4; ++k) {
                float4 g4 = *(const float4*)&gp[(d4 + k) * C_CLS];
                v2f glo = {g4.x, g4.y}, ghi = {g4.z, g4.w};
#pragma unroll
                for (int si = 0; si < SAMP; ++si) {
                    float x = xr[si][k];
                    v2f x2 = {x, x};
                    v2f el = x2 - glo;
                    v2f eh = x2 - ghi;
                    l1[si][0] += fabsf(el.x);
                    l1[si][1] += fabsf(el.y);
                    l1[si][2] += fabsf(eh.x);
                    l1[si][3] += fabsf(eh.y);
                    dtl[si] += x2 * glo;
                    dth[si] += x2 * ghi;
                }
            }
        }
        // in-wave dq reduction: lanes (t&7) = 0..7 hold partials for same cq
#pragma unroll
        for (int m = 1; m <= 4; m <<= 1) {
#pragma unroll
            for (int si = 0; si < SAMP; ++si) {
#pragma unroll
                for (int c = 0; c < 4; ++c) l1[si][c] += __shfl_xor(l1[si][c], m);
                dtl[si].x += __shfl_xor(dtl[si].x, m);
                dtl[si].y += __shfl_xor(dtl[si].y, m);
                dth[si].x += __shfl_xor(dth[si].x, m);
                dth[si].y += __shfl_xor(dth[si].y, m);
            }
        }
        if (dq == 0) {
#pragma unroll
            for (int si = 0; si < SAMP; ++si) {
                pL1[si][cq] = float4{l1[si][0], l1[si][1], l1[si][2], l1[si][3]};
                pDT[si][cq] = float4{dtl[si].x, dtl[si].y, dth[si].x, dth[si].y};
            }
        }
    }
    __syncthreads();

    // fin: thread (s = t/25 in 0..3, c2 = t%25)
    const int s  = t / 25;
    const int c2 = t - s * 25;
    const bool act2 = (t < 100);

    float l1c[4] = {0.f, 0.f, 0.f, 0.f};
    float cs[4]  = {0.f, 0.f, 0.f, 0.f};
    if (act2) {
        float4 a = pL1[s][c2];
        float4 b = pDT[s][c2];
        float4 gq = *(const float4*)&gsq[c2 * 4];
        float xq = xsqs[s];
        l1c[0] = a.x; l1c[1] = a.y; l1c[2] = a.z; l1c[3] = a.w;
        cs[0] = b.x / fmaxf(sqrtf(xq * gq.x), 1e-8f);
        cs[1] = b.y / fmaxf(sqrtf(xq * gq.y), 1e-8f);
        cs[2] = b.z / fmaxf(sqrtf(xq * gq.z), 1e-8f);
        cs[3] = b.w / fmaxf(sqrtf(xq * gq.w), 1e-8f);
        redA[s][c2] = fminf(fminf(l1c[0], l1c[1]), fminf(l1c[2], l1c[3]));
        redB[s][c2] = fmaxf(fmaxf(cs[0], cs[1]), fmaxf(cs[2], cs[3]));
    }
    __syncthreads();

    float minl1 = 0.f, maxcs = 0.f;
    if (act2) {
        minl1 = redA[s][0];
        maxcs = redB[s][0];
        for (int k = 1; k < 25; ++k) {
            minl1 = fminf(minl1, redA[s][k]);
            maxcs = fmaxf(maxcs, redB[s][k]);
        }
    }
    __syncthreads();

    if (act2) {
        redA[s][c2] = __expf(minl1 - l1c[0]) + __expf(minl1 - l1c[1]) +
                      __expf(minl1 - l1c[2]) + __expf(minl1 - l1c[3]);
        redB[s][c2] = __expf(cs[0] - maxcs) + __expf(cs[1] - maxcs) +
                      __expf(cs[2] - maxcs) + __expf(cs[3] - maxcs);
    }
    __syncthreads();

    if (act2) {
        float s1 = 0.f, s2 = 0.f;
        for (int k = 0; k < 25; ++k) { s1 += redA[s][k]; s2 += redB[s][k]; }
        float f = maxcs / (s1 * s2);
        float4 o;
        o.x = f * __expf(cs[0] - maxcs) * __expf(minl1 - l1c[0]);
        o.y = f * __expf(cs[1] - maxcs) * __expf(minl1 - l1c[1]);
        o.z = f * __expf(cs[2] - maxcs) * __expf(minl1 - l1c[2]);
        o.w = f * __expf(cs[3] - maxcs) * __expf(minl1 - l1c[3]);
        *(float4*)&out[(size_t)(n0 + s) * C_CLS + c2 * 4] = o;
    }
}

extern "C" void kernel_launch(void* const* d_in, const int* in_sizes, int n_in,
                              void* d_out, int out_size, void* d_ws, size_t ws_size,
                              hipStream_t stream) {
    const float* X   = (const float*)d_in[0];   // [4096, 512] f32
    const float* grp = (const float*)d_in[1];   // [1, 512, 100] f32
    float* out = (float*)d_out;                 // [4096, 100] f32
    float* ws  = (float*)d_ws;                  // gsq: 100 floats

    gsq_kernel<<<25, 128, 0, stream>>>(grp, ws);
    cls_kernel<<<4096 / SAMP, NT, 0, stream>>>(X, grp, ws, out);
}